// Round 13
// baseline (5672.879 us; speedup 1.0000x reference)
//
#include <hip/hip_runtime.h>
#include <hip/hip_cooperative_groups.h>

namespace cg = cooperative_groups;

#define CH     16
#define HID    128
#define HWDIM  128
#define NB     32
#define NSTEPS 32

typedef float    f32x4 __attribute__((ext_vector_type(4)));
typedef _Float16 f16x4 __attribute__((ext_vector_type(4)));
typedef _Float16 f16x8 __attribute__((ext_vector_type(8)));

// compile-time ordering fence: per-wave DS ops complete in order in HW, so
// emission order == correctness for wave-private LDS (round-3+ verified).
#define MEMBAR() asm volatile("" ::: "memory")

// ---------------------------------------------------------------------------
// Prepack weights into per-lane MFMA fragment order (fp16).
// A/B frag layout (16x16x32): lane l -> row/col = l&15, k = 8*(l>>4)+j.
// pw0 (A-operand W0): 16 frags, f = n*2+ks (n = hidden 16-tile, K pad 48->64)
// pw1 (A-operand W1): 4 frags,  f = ks (K over 128)
// ---------------------------------------------------------------------------
__global__ __launch_bounds__(256) void nca_prepack(
    const float* __restrict__ w0, const float* __restrict__ w1,
    _Float16* __restrict__ pw0, _Float16* __restrict__ pw1)
{
    const int tid = threadIdx.x;
    for (int s = tid; s < 16 * 64; s += 256) {
        const int f = s >> 6, l = s & 63;
        const int n = f >> 1, ks = f & 1;
        const int o = 16 * n + (l & 15);
        f16x8 v;
        #pragma unroll
        for (int j = 0; j < 8; ++j) {
            const int k = 32 * ks + 8 * (l >> 4) + j;
            v[j] = (_Float16)(k < 48 ? w0[o * 48 + k] : 0.f);
        }
        *reinterpret_cast<f16x8*>(&pw0[s * 8]) = v;
    }
    for (int s = tid; s < 4 * 64; s += 256) {
        const int ks = s >> 6, l = s & 63;
        f16x8 v;
        #pragma unroll
        for (int j = 0; j < 8; ++j) {
            const int k = 32 * ks + 8 * (l >> 4) + j;
            v[j] = (_Float16)w1[(l & 15) * 128 + k];
        }
        *reinterpret_cast<f16x8*>(&pw1[s * 8]) = v;
    }
}

// ---------------------------------------------------------------------------
// One tile of one NCA step — r12-verbatim compute (verified absmax 0.03125).
//
// CACHE EQUILIBRIUM RULES (measured r3/r9/r11/r12 vs r5-r8/r10):
//   (1) exactly 4 blocks/CU (LDS 36864 + launch_bounds(256,4)).
//   (2) tile->XCD affinity constant across steps (bx = block&7).
//   (3) epilogue re-reads xin[pix] right before storing xout[pix].
//
// LDS pool 36864 B: phase A halo f32 [18][18][20] (cross-wave, barriers);
//   phase B per-wave 9216 B slices: ybuf[64][144 B] -> hbuf[64][80 B]
//   -> dbuf[64][20 f32]  (wave-private, MEMBAR ordering only).
// POOL: block-reduce channel sums -> partial[tile][16]; redbuf OVERLAYS the
// dead wave slices (extra barrier), so LDS stays 36864.
// ---------------------------------------------------------------------------
template <bool POOL>
__device__ __forceinline__ void process_tile(
    char* pool, const int tile,
    const float* __restrict__ xin, float* __restrict__ xout,
    const float* __restrict__ mask,
    const _Float16* __restrict__ pw0, const float* __restrict__ fc0_b,
    const _Float16* __restrict__ pw1, float* __restrict__ partial)
{
    float (*halo)[18][20] = reinterpret_cast<float(*)[18][20]>(pool);

    const int tid = threadIdx.x;
    const int w = tid >> 6, l = tid & 63;
    const int lr = l & 15, g = l >> 4;
    const int bz  = tile >> 6;
    const int ty0 = ((tile >> 3) & 7) * 16, tx0 = (tile & 7) * 16;

    __syncthreads();     // WAR: previous tile/step's LDS use done

    // ---- stage halo, pixel-major f32, pitch 20 floats (bank-safe) ----
    for (int q = tid; q < 18 * 18 * 4; q += 256) {
        const int c4 = q & 3, p = q >> 2;
        const int ii = p / 18, jj = p - ii * 18;
        const int gy = ty0 - 1 + ii, gx = tx0 - 1 + jj;
        f32x4 v = {0.f, 0.f, 0.f, 0.f};
        if ((unsigned)gy < HWDIM && (unsigned)gx < HWDIM)
            v = *reinterpret_cast<const f32x4*>(
                &xin[(((size_t)bz * HWDIM + gy) * HWDIM + gx) * CH + 4 * c4]);
        *reinterpret_cast<f32x4*>(&halo[ii][jj][4 * c4]) = v;
    }
    __syncthreads();     // halo staged

    // ---- perception (f32, shared 9-tap loads), results as f16 in regs ----
    const int j = tid & 15, i = tid >> 4;
    const int li = i + 1, lj = j + 1;
    _Float16 idv[16], dxv[16], dyv[16];
    #pragma unroll
    for (int c4 = 0; c4 < 4; ++c4) {
        #define HLD(dy, dx) (*reinterpret_cast<const f32x4*>(&halo[li + (dy)][lj + (dx)][4 * c4]))
        const f32x4 n00 = HLD(-1,-1), n01 = HLD(-1,0), n02 = HLD(-1,1);
        const f32x4 n10 = HLD( 0,-1), n11 = HLD( 0,0), n12 = HLD( 0,1);
        const f32x4 n20 = HLD( 1,-1), n21 = HLD( 1,0), n22 = HLD( 1,1);
        #undef HLD
        const f32x4 gx = ((n02 - n00) + 2.f * (n12 - n10) + (n22 - n20)) * 0.125f;
        const f32x4 gy = ((n20 - n00) + 2.f * (n21 - n01) + (n22 - n02)) * 0.125f;
        #pragma unroll
        for (int e = 0; e < 4; ++e) {
            idv[4 * c4 + e] = (_Float16)n11[e];
            dxv[4 * c4 + e] = (_Float16)gx[e];
            dyv[4 * c4 + e] = (_Float16)gy[e];
        }
    }
    __syncthreads();     // ALL waves' halo reads done before ybuf clobbers halo

    char* wreg = pool + w * 9216;          // this wave's private slice

    // ---- ybuf write: own row l, pitch 144 B; cols 0..47 = y, 48..63 = 0 ----
    {
        _Float16* yrow = reinterpret_cast<_Float16*>(wreg + l * 144);
        f16x8 v;
        #pragma unroll
        for (int e = 0; e < 8; ++e) v[e] = idv[e];
        *reinterpret_cast<f16x8*>(&yrow[0]) = v;
        #pragma unroll
        for (int e = 0; e < 8; ++e) v[e] = idv[8 + e];
        *reinterpret_cast<f16x8*>(&yrow[8]) = v;
        #pragma unroll
        for (int e = 0; e < 8; ++e) v[e] = dxv[e];
        *reinterpret_cast<f16x8*>(&yrow[16]) = v;
        #pragma unroll
        for (int e = 0; e < 8; ++e) v[e] = dxv[8 + e];
        *reinterpret_cast<f16x8*>(&yrow[24]) = v;
        #pragma unroll
        for (int e = 0; e < 8; ++e) v[e] = dyv[e];
        *reinterpret_cast<f16x8*>(&yrow[32]) = v;
        #pragma unroll
        for (int e = 0; e < 8; ++e) v[e] = dyv[8 + e];
        *reinterpret_cast<f16x8*>(&yrow[40]) = v;
        f16x8 z;
        #pragma unroll
        for (int e = 0; e < 8; ++e) z[e] = (_Float16)0.f;
        *reinterpret_cast<f16x8*>(&yrow[48]) = z;   // K-pad 48..63 = 0
        *reinterpret_cast<f16x8*>(&yrow[56]) = z;
    }
    MEMBAR();

    // ---- Y fragments (MFMA B operand: col = pixel 16t+lr, k = 8g+j) ----
    f16x8 afrag[8];
    #pragma unroll
    for (int t = 0; t < 4; ++t)
        #pragma unroll
        for (int ks = 0; ks < 2; ++ks)
            afrag[2 * t + ks] = *reinterpret_cast<const f16x8*>(
                wreg + (16 * t + lr) * 144 + 64 * ks + 16 * g);
    MEMBAR();

    // ---- W1 fragments (A operand) ----
    f16x8 b1f[4];
    #pragma unroll
    for (int ks = 0; ks < 4; ++ks)
        b1f[ks] = *reinterpret_cast<const f16x8*>(&pw1[(ks * 64 + l) * 8]);

    f32x4 dacc[4];
    #pragma unroll
    for (int t = 0; t < 4; ++t)
        #pragma unroll
        for (int r = 0; r < 4; ++r) dacc[t][r] = 0.f;

    // ---- 4 chunks of 32 hidden: H^T = relu(W0*Y^T + b), d^T += W1*H ----
    _Float16* hb = reinterpret_cast<_Float16*>(wreg);   // [64 px][80 B] f16
    #pragma unroll
    for (int c = 0; c < 4; ++c) {
        f16x8 b0f[4];
        #pragma unroll
        for (int q = 0; q < 4; ++q)
            b0f[q] = *reinterpret_cast<const f16x8*>(&pw0[((4 * c + q) * 64 + l) * 8]);
        const f32x4 bq0 = *reinterpret_cast<const f32x4*>(&fc0_b[32 * c + 4 * g]);
        const f32x4 bq1 = *reinterpret_cast<const f32x4*>(&fc0_b[32 * c + 16 + 4 * g]);
        #pragma unroll
        for (int nl = 0; nl < 2; ++nl) {
            const f32x4 bq = nl ? bq1 : bq0;
            #pragma unroll
            for (int t = 0; t < 4; ++t) {
                f32x4 acc = {0.f, 0.f, 0.f, 0.f};
                acc = __builtin_amdgcn_mfma_f32_16x16x32_f16(b0f[2*nl+0], afrag[2*t+0], acc, 0, 0, 0);
                acc = __builtin_amdgcn_mfma_f32_16x16x32_f16(b0f[2*nl+1], afrag[2*t+1], acc, 0, 0, 0);
                // D^T: row = hidden 16nl+4g+r, col = pixel 16t+lr
                f16x4 hv;
                #pragma unroll
                for (int r = 0; r < 4; ++r)
                    hv[r] = (_Float16)fmaxf(acc[r] + bq[r], 0.f);
                *reinterpret_cast<f16x4*>(
                    reinterpret_cast<char*>(hb) + (16 * t + lr) * 80 + 32 * nl + 8 * g) = hv;
            }
        }
        MEMBAR();        // wave-private in-order DS: writes before reads
        #pragma unroll
        for (int t = 0; t < 4; ++t)
            dacc[t] = __builtin_amdgcn_mfma_f32_16x16x32_f16(
                b1f[c],
                *reinterpret_cast<const f16x8*>(
                    reinterpret_cast<const char*>(hb) + (16 * t + lr) * 80 + 16 * g),
                dacc[t], 0, 0, 0);
        MEMBAR();        // WAR before next chunk's writes
    }

    // ---- transpose d to thread-pixel layout: 4 ds_write_b128 per lane ----
    float* db = reinterpret_cast<float*>(wreg);         // [64 px][20] f32
    #pragma unroll
    for (int t = 0; t < 4; ++t)
        *reinterpret_cast<f32x4*>(&db[(16 * t + lr) * 20 + 4 * g]) = dacc[t];
    MEMBAR();

    // ---- epilogue: xin re-read + float mask (equilibrium rule (3)) ----
    f32x4 ov[4];
    {
        const size_t pix = ((size_t)bz * HWDIM + (ty0 + i)) * HWDIM + (tx0 + j);
        const float m = mask[pix];
        const float* dp = db + l * 20;
        const f32x4* xi4 = reinterpret_cast<const f32x4*>(&xin[pix * CH]);
        f32x4* xo4 = reinterpret_cast<f32x4*>(&xout[pix * CH]);
        const f32x4 dv = *reinterpret_cast<const f32x4*>(&dp[0]);
        f32x4 v0 = xi4[0];                  // ch 0..2 frozen (exact copy)
        v0[3] += dv[3] * m;
        xo4[0] = v0;
        ov[0] = v0;
        #pragma unroll
        for (int q = 1; q < 4; ++q) {
            const f32x4 d4 = *reinterpret_cast<const f32x4*>(&dp[4 * q]);
            f32x4 v = xi4[q];
            #pragma unroll
            for (int e = 0; e < 4; ++e) v[e] += d4[e] * m;
            xo4[q] = v;
            ov[q] = v;
        }
    }

    // ---- POOL (last step): block-reduce channel sums -> partial ----
    if (POOL) {
        __syncthreads();     // all waves' db reads done before redbuf overlays slices
        float* red = reinterpret_cast<float*>(pool);           // [256][16] overlay
        #pragma unroll
        for (int q = 0; q < 4; ++q)
            *reinterpret_cast<f32x4*>(&red[tid * CH + 4 * q]) = ov[q];
        __syncthreads();
        for (int off = 128; off > 0; off >>= 1) {
            if (tid < off) {
                #pragma unroll
                for (int c = 0; c < CH; ++c)
                    red[tid * CH + c] += red[(tid + off) * CH + c];
            }
            __syncthreads();
        }
        if (tid < CH)
            partial[tile * CH + tid] = red[tid];
    }
}

// ---------------------------------------------------------------------------
// Persistent cooperative kernel: all 32 steps, grid-wide sync between steps.
// 1024 blocks = exactly 4 blocks/CU co-resident; each block owns 2 fixed
// tiles (blockIdx.x, blockIdx.x+1024) for ALL steps -> stable XCD affinity.
// ---------------------------------------------------------------------------
__global__ __launch_bounds__(256, 4) void nca_run(
    const float* __restrict__ x0,
    float* __restrict__ xf, float* __restrict__ buf0,
    const float* __restrict__ masks,
    const _Float16* __restrict__ pw0, const float* __restrict__ fc0_b,
    const _Float16* __restrict__ pw1, float* __restrict__ partial)
{
    cg::grid_group gg = cg::this_grid();
    __shared__ __align__(16) char pool[36864];

    #pragma unroll 1
    for (int s = 0; s < NSTEPS; ++s) {
        const float* xin = (s == 0) ? x0 : ((s & 1) ? buf0 : xf);
        float* xout      = (s & 1) ? xf : buf0;
        const float* mk  = masks + (size_t)s * (NB * HWDIM * HWDIM);
        if (s == NSTEPS - 1) {
            #pragma unroll 1
            for (int rep = 0; rep < 2; ++rep)
                process_tile<true>(pool, (int)blockIdx.x + (rep << 10),
                                   xin, xout, mk, pw0, fc0_b, pw1, partial);
        } else {
            #pragma unroll 1
            for (int rep = 0; rep < 2; ++rep)
                process_tile<false>(pool, (int)blockIdx.x + (rep << 10),
                                    xin, xout, mk, pw0, fc0_b, pw1, partial);
            gg.sync();       // next step may read this step's writes
        }
    }
}

// ---------------------------------------------------------------------------
// Fallback per-step kernel (r12 path), used if cooperative launch fails.
// ---------------------------------------------------------------------------
template <bool POOL>
__global__ __launch_bounds__(256, 4) void nca_step(
    const float* __restrict__ xin, float* __restrict__ xout,
    const float* __restrict__ mask,
    const _Float16* __restrict__ pw0, const float* __restrict__ fc0_b,
    const _Float16* __restrict__ pw1, float* __restrict__ partial)
{
    __shared__ __align__(16) char pool[36864];
    const int tile = ((int)blockIdx.z * 8 + (int)blockIdx.y) * 8 + (int)blockIdx.x;
    process_tile<POOL>(pool, tile, xin, xout, mask, pw0, fc0_b, pw1, partial);
}

// ---------------------------------------------------------------------------
// Classifier head, one block per batch: sum 64 tile-partials -> fc2 -> fc3.
// ---------------------------------------------------------------------------
__global__ __launch_bounds__(128) void nca_head(
    const float* __restrict__ partial,
    const float* __restrict__ fc2_w, const float* __restrict__ fc2_b,
    const float* __restrict__ fc3_w, const float* __restrict__ fc3_b,
    float* __restrict__ out)
{
    __shared__ float h2[HID];
    __shared__ float pl[CH];
    const int tid = threadIdx.x, b = blockIdx.x;
    if (tid < CH) {
        float s = 0.f;
        #pragma unroll
        for (int q = 0; q < 64; ++q) s += partial[(b * 64 + q) * CH + tid];
        pl[tid] = s * (1.f / (HWDIM * HWDIM));
    }
    __syncthreads();
    float h = fc2_b[tid];
    #pragma unroll
    for (int c = 0; c < CH; ++c) h += fc2_w[tid * CH + c] * pl[c];
    h2[tid] = fmaxf(h, 0.f);
    __syncthreads();
    if (tid < 13) {
        float o = fc3_b[tid];
        #pragma unroll
        for (int jj = 0; jj < HID; ++jj) o += fc3_w[tid * HID + jj] * h2[jj];
        out[b * 13 + tid] = o;
    }
}

// ---------------------------------------------------------------------------
extern "C" void kernel_launch(void* const* d_in, const int* in_sizes, int n_in,
                              void* d_out, int out_size, void* d_ws, size_t ws_size,
                              hipStream_t stream)
{
    const float* x     = (const float*)d_in[0];
    const float* masks = (const float*)d_in[1];
    const float* fc0_w = (const float*)d_in[2];
    const float* fc0_b = (const float*)d_in[3];
    const float* fc1_w = (const float*)d_in[4];
    const float* fc2_w = (const float*)d_in[5];
    const float* fc2_b = (const float*)d_in[6];
    const float* fc3_w = (const float*)d_in[7];
    const float* fc3_b = (const float*)d_in[8];

    float*    out     = (float*)d_out;
    float*    xf      = out + NB * 13;                             // output 1 region
    float*    buf0    = (float*)d_ws;                              // ping-pong state
    float*    partial = buf0 + (size_t)NB * HWDIM * HWDIM * CH;    // 2048*16 f
    _Float16* pw0     = (_Float16*)(partial + 2048 * CH);          // 16 KiB
    _Float16* pw1     = pw0 + 16 * 64 * 8;                         // 4 KiB

    nca_prepack<<<1, 256, 0, stream>>>(fc0_w, fc1_w, pw0, pw1);

    // ---- persistent cooperative kernel: all 32 steps, one launch ----
    const float*    a0 = x;
    float*          a1 = xf;
    float*          a2 = buf0;
    const float*    a3 = masks;
    const _Float16* a4 = pw0;
    const float*    a5 = fc0_b;
    const _Float16* a6 = pw1;
    float*          a7 = partial;
    void* args[] = {&a0, &a1, &a2, &a3, &a4, &a5, &a6, &a7};
    hipError_t err = hipLaunchCooperativeKernel(
        reinterpret_cast<const void*>(&nca_run),
        dim3(1024), dim3(256), args, 0, stream);

    if (err != hipSuccess) {
        // fallback: r12 per-step launches (same process_tile, same results)
        dim3 grid(HWDIM / 16, HWDIM / 16, NB), block(256);
        for (int s = 0; s < NSTEPS; ++s) {
            const float* in = (s == 0) ? x : ((s & 1) ? buf0 : xf);
            float* outp     = (s & 1) ? xf : buf0;
            const float* mk = masks + (size_t)s * NB * HWDIM * HWDIM;
            if (s == NSTEPS - 1)
                nca_step<true><<<grid, block, 0, stream>>>(in, outp, mk, pw0, fc0_b, pw1, partial);
            else
                nca_step<false><<<grid, block, 0, stream>>>(in, outp, mk, pw0, fc0_b, pw1, partial);
        }
    }

    nca_head<<<NB, 128, 0, stream>>>(partial, fc2_w, fc2_b, fc3_w, fc3_b, out);
}

// Round 14
// 889.966 us; speedup vs baseline: 6.3743x; 6.3743x over previous
//
#include <hip/hip_runtime.h>

#define CH     16
#define HID    128
#define HWDIM  128
#define NB     32
#define NSTEPS 32

typedef float    f32x4 __attribute__((ext_vector_type(4)));
typedef _Float16 f16x4 __attribute__((ext_vector_type(4)));
typedef _Float16 f16x8 __attribute__((ext_vector_type(8)));

// compile-time ordering fence: per-wave DS ops complete in order in HW, so
// emission order == correctness for wave-private LDS (round-3+ verified).
#define MEMBAR() asm volatile("" ::: "memory")

// ---------------------------------------------------------------------------
// Prepack weights into per-lane MFMA fragment order (fp16).
// A/B frag layout (16x16x32): lane l -> row/col = l&15, k = 8*(l>>4)+j.
// pw0 (A-operand W0): 16 frags, f = n*2+ks (n = hidden 16-tile, K pad 48->64)
// pw1 (A-operand W1): 4 frags,  f = ks (K over 128)
// ---------------------------------------------------------------------------
__global__ __launch_bounds__(256) void nca_prepack(
    const float* __restrict__ w0, const float* __restrict__ w1,
    _Float16* __restrict__ pw0, _Float16* __restrict__ pw1)
{
    const int tid = threadIdx.x;
    for (int s = tid; s < 16 * 64; s += 256) {
        const int f = s >> 6, l = s & 63;
        const int n = f >> 1, ks = f & 1;
        const int o = 16 * n + (l & 15);
        f16x8 v;
        #pragma unroll
        for (int j = 0; j < 8; ++j) {
            const int k = 32 * ks + 8 * (l >> 4) + j;
            v[j] = (_Float16)(k < 48 ? w0[o * 48 + k] : 0.f);
        }
        *reinterpret_cast<f16x8*>(&pw0[s * 8]) = v;
    }
    for (int s = tid; s < 4 * 64; s += 256) {
        const int ks = s >> 6, l = s & 63;
        f16x8 v;
        #pragma unroll
        for (int j = 0; j < 8; ++j) {
            const int k = 32 * ks + 8 * (l >> 4) + j;
            v[j] = (_Float16)w1[(l & 15) * 128 + k];
        }
        *reinterpret_cast<f16x8*>(&pw1[s * 8]) = v;
    }
}

// ---------------------------------------------------------------------------
// One NCA step — consolidated best of 13 rounds (r12 + POOL redbuf overlay).
//
// CACHE EQUILIBRIUM RULES (measured r3/r9/r11/r12 vs r5-r8/r10/r13):
//   (1) exactly 4 blocks/CU (LDS 36864 + launch_bounds(256,4)); more blocks
//       thrashes per-XCD L2: FETCH 23->100 MB, WRITE 33->185 MB (r10).
//   (2) grid (8,8,32): block->XCD affinity constant across steps (inter-step
//       L2 retention: FETCH 23.4 < 33.5 MB input).
//   (3) epilogue re-reads xin[pix] right before storing xout[pix]; removing
//       it inflated WRITE 2.2-3.5x (r5/r6/r8).
//   (4) per-step launches, NOT cooperative: grid.sync costs ~140us/sync and
//       its fences destroy L2 retention (r13: 6.7x regression).
// Perception via ybuf round-trip (r9) beats fragment-direct (r11) by ~3 us.
//
// LDS pool 36864 B: phase A halo f32 [18][18][20] (cross-wave, 2 barriers);
//   phase B per-wave 9216 B slices: ybuf[64][144 B] -> hbuf[64][80 B]
//   -> dbuf[64][20 f32]  (wave-private, MEMBAR ordering only).
// POOL=true (step 31): block-reduce channel sums -> partial[tile][16];
// redbuf OVERLAYS dead wave slices (extra barrier) so LDS stays 36864.
// ---------------------------------------------------------------------------
template <bool POOL>
__global__ __launch_bounds__(256, 4) void nca_step(
    const float* __restrict__ xin, float* __restrict__ xout,
    const float* __restrict__ mask,
    const _Float16* __restrict__ pw0, const float* __restrict__ fc0_b,
    const _Float16* __restrict__ pw1, float* __restrict__ partial)
{
    __shared__ __align__(16) char pool[36864];
    float (*halo)[18][20] = reinterpret_cast<float(*)[18][20]>(pool);

    const int tid = threadIdx.x;
    const int w = tid >> 6, l = tid & 63;
    const int lr = l & 15, g = l >> 4;
    const int bz = blockIdx.z;
    const int y0 = blockIdx.y * 16, x0 = blockIdx.x * 16;

    // ---- stage halo, pixel-major f32, pitch 20 floats (bank-safe) ----
    for (int q = tid; q < 18 * 18 * 4; q += 256) {
        const int c4 = q & 3, p = q >> 2;
        const int ii = p / 18, jj = p - ii * 18;
        const int gy = y0 - 1 + ii, gx = x0 - 1 + jj;
        f32x4 v = {0.f, 0.f, 0.f, 0.f};
        if ((unsigned)gy < HWDIM && (unsigned)gx < HWDIM)
            v = *reinterpret_cast<const f32x4*>(
                &xin[(((size_t)bz * HWDIM + gy) * HWDIM + gx) * CH + 4 * c4]);
        *reinterpret_cast<f32x4*>(&halo[ii][jj][4 * c4]) = v;
    }
    __syncthreads();     // halo staged

    // ---- perception (f32, shared 9-tap loads), results as f16 in regs ----
    const int j = tid & 15, i = tid >> 4;
    const int li = i + 1, lj = j + 1;
    _Float16 idv[16], dxv[16], dyv[16];
    #pragma unroll
    for (int c4 = 0; c4 < 4; ++c4) {
        #define HLD(dy, dx) (*reinterpret_cast<const f32x4*>(&halo[li + (dy)][lj + (dx)][4 * c4]))
        const f32x4 n00 = HLD(-1,-1), n01 = HLD(-1,0), n02 = HLD(-1,1);
        const f32x4 n10 = HLD( 0,-1), n11 = HLD( 0,0), n12 = HLD( 0,1);
        const f32x4 n20 = HLD( 1,-1), n21 = HLD( 1,0), n22 = HLD( 1,1);
        #undef HLD
        const f32x4 gx = ((n02 - n00) + 2.f * (n12 - n10) + (n22 - n20)) * 0.125f;
        const f32x4 gy = ((n20 - n00) + 2.f * (n21 - n01) + (n22 - n02)) * 0.125f;
        #pragma unroll
        for (int e = 0; e < 4; ++e) {
            idv[4 * c4 + e] = (_Float16)n11[e];
            dxv[4 * c4 + e] = (_Float16)gx[e];
            dyv[4 * c4 + e] = (_Float16)gy[e];
        }
    }
    __syncthreads();     // ALL waves' halo reads done before ybuf clobbers halo

    char* wreg = pool + w * 9216;          // this wave's private slice

    // ---- ybuf write: own row l, pitch 144 B; cols 0..47 = y, 48..63 = 0 ----
    {
        _Float16* yrow = reinterpret_cast<_Float16*>(wreg + l * 144);
        f16x8 v;
        #pragma unroll
        for (int e = 0; e < 8; ++e) v[e] = idv[e];
        *reinterpret_cast<f16x8*>(&yrow[0]) = v;
        #pragma unroll
        for (int e = 0; e < 8; ++e) v[e] = idv[8 + e];
        *reinterpret_cast<f16x8*>(&yrow[8]) = v;
        #pragma unroll
        for (int e = 0; e < 8; ++e) v[e] = dxv[e];
        *reinterpret_cast<f16x8*>(&yrow[16]) = v;
        #pragma unroll
        for (int e = 0; e < 8; ++e) v[e] = dxv[8 + e];
        *reinterpret_cast<f16x8*>(&yrow[24]) = v;
        #pragma unroll
        for (int e = 0; e < 8; ++e) v[e] = dyv[e];
        *reinterpret_cast<f16x8*>(&yrow[32]) = v;
        #pragma unroll
        for (int e = 0; e < 8; ++e) v[e] = dyv[8 + e];
        *reinterpret_cast<f16x8*>(&yrow[40]) = v;
        f16x8 z;
        #pragma unroll
        for (int e = 0; e < 8; ++e) z[e] = (_Float16)0.f;
        *reinterpret_cast<f16x8*>(&yrow[48]) = z;   // K-pad 48..63 = 0
        *reinterpret_cast<f16x8*>(&yrow[56]) = z;
    }
    MEMBAR();

    // ---- Y fragments (MFMA B operand: col = pixel 16t+lr, k = 8g+j) ----
    f16x8 afrag[8];
    #pragma unroll
    for (int t = 0; t < 4; ++t)
        #pragma unroll
        for (int ks = 0; ks < 2; ++ks)
            afrag[2 * t + ks] = *reinterpret_cast<const f16x8*>(
                wreg + (16 * t + lr) * 144 + 64 * ks + 16 * g);
    MEMBAR();

    // ---- W1 fragments (A operand) ----
    f16x8 b1f[4];
    #pragma unroll
    for (int ks = 0; ks < 4; ++ks)
        b1f[ks] = *reinterpret_cast<const f16x8*>(&pw1[(ks * 64 + l) * 8]);

    f32x4 dacc[4];
    #pragma unroll
    for (int t = 0; t < 4; ++t)
        #pragma unroll
        for (int r = 0; r < 4; ++r) dacc[t][r] = 0.f;

    // ---- 4 chunks of 32 hidden: H^T = relu(W0*Y^T + b), d^T += W1*H ----
    _Float16* hb = reinterpret_cast<_Float16*>(wreg);   // [64 px][80 B] f16
    #pragma unroll
    for (int c = 0; c < 4; ++c) {
        f16x8 b0f[4];
        #pragma unroll
        for (int q = 0; q < 4; ++q)
            b0f[q] = *reinterpret_cast<const f16x8*>(&pw0[((4 * c + q) * 64 + l) * 8]);
        const f32x4 bq0 = *reinterpret_cast<const f32x4*>(&fc0_b[32 * c + 4 * g]);
        const f32x4 bq1 = *reinterpret_cast<const f32x4*>(&fc0_b[32 * c + 16 + 4 * g]);
        #pragma unroll
        for (int nl = 0; nl < 2; ++nl) {
            const f32x4 bq = nl ? bq1 : bq0;
            #pragma unroll
            for (int t = 0; t < 4; ++t) {
                f32x4 acc = {0.f, 0.f, 0.f, 0.f};
                acc = __builtin_amdgcn_mfma_f32_16x16x32_f16(b0f[2*nl+0], afrag[2*t+0], acc, 0, 0, 0);
                acc = __builtin_amdgcn_mfma_f32_16x16x32_f16(b0f[2*nl+1], afrag[2*t+1], acc, 0, 0, 0);
                // D^T: row = hidden 16nl+4g+r, col = pixel 16t+lr
                f16x4 hv;
                #pragma unroll
                for (int r = 0; r < 4; ++r)
                    hv[r] = (_Float16)fmaxf(acc[r] + bq[r], 0.f);
                *reinterpret_cast<f16x4*>(
                    reinterpret_cast<char*>(hb) + (16 * t + lr) * 80 + 32 * nl + 8 * g) = hv;
            }
        }
        MEMBAR();        // wave-private in-order DS: writes before reads
        #pragma unroll
        for (int t = 0; t < 4; ++t)
            dacc[t] = __builtin_amdgcn_mfma_f32_16x16x32_f16(
                b1f[c],
                *reinterpret_cast<const f16x8*>(
                    reinterpret_cast<const char*>(hb) + (16 * t + lr) * 80 + 16 * g),
                dacc[t], 0, 0, 0);
        MEMBAR();        // WAR before next chunk's writes
    }

    // ---- transpose d to thread-pixel layout: 4 ds_write_b128 per lane ----
    float* db = reinterpret_cast<float*>(wreg);         // [64 px][20] f32
    #pragma unroll
    for (int t = 0; t < 4; ++t)
        *reinterpret_cast<f32x4*>(&db[(16 * t + lr) * 20 + 4 * g]) = dacc[t];
    MEMBAR();

    // ---- epilogue: xin re-read + float mask (equilibrium rule (3)) ----
    f32x4 ov[4];
    {
        const size_t pix = ((size_t)bz * HWDIM + (y0 + i)) * HWDIM + (x0 + j);
        const float m = mask[pix];
        const float* dp = db + l * 20;
        const f32x4* xi4 = reinterpret_cast<const f32x4*>(&xin[pix * CH]);
        f32x4* xo4 = reinterpret_cast<f32x4*>(&xout[pix * CH]);
        const f32x4 dv = *reinterpret_cast<const f32x4*>(&dp[0]);
        f32x4 v0 = xi4[0];                  // ch 0..2 frozen (exact copy)
        v0[3] += dv[3] * m;
        xo4[0] = v0;
        ov[0] = v0;
        #pragma unroll
        for (int q = 1; q < 4; ++q) {
            const f32x4 d4 = *reinterpret_cast<const f32x4*>(&dp[4 * q]);
            f32x4 v = xi4[q];
            #pragma unroll
            for (int e = 0; e < 4; ++e) v[e] += d4[e] * m;
            xo4[q] = v;
            ov[q] = v;
        }
    }

    // ---- POOL (step 31 only): block-reduce channel sums -> partial;
    //      redbuf overlays the dead wave slices, LDS stays 36864 ----
    if (POOL) {
        __syncthreads();     // all waves' db reads done before redbuf overlay
        float* red = reinterpret_cast<float*>(pool);           // [256][16]
        #pragma unroll
        for (int q = 0; q < 4; ++q)
            *reinterpret_cast<f32x4*>(&red[tid * CH + 4 * q]) = ov[q];
        __syncthreads();
        for (int off = 128; off > 0; off >>= 1) {
            if (tid < off) {
                #pragma unroll
                for (int c = 0; c < CH; ++c)
                    red[tid * CH + c] += red[(tid + off) * CH + c];
            }
            __syncthreads();
        }
        if (tid < CH) {
            const int tile = (bz * 8 + blockIdx.y) * 8 + blockIdx.x;
            partial[tile * CH + tid] = red[tid];
        }
    }
}

// ---------------------------------------------------------------------------
// Classifier head, one block per batch: sum 64 tile-partials -> fc2 -> fc3.
// ---------------------------------------------------------------------------
__global__ __launch_bounds__(128) void nca_head(
    const float* __restrict__ partial,
    const float* __restrict__ fc2_w, const float* __restrict__ fc2_b,
    const float* __restrict__ fc3_w, const float* __restrict__ fc3_b,
    float* __restrict__ out)
{
    __shared__ float h2[HID];
    __shared__ float pl[CH];
    const int tid = threadIdx.x, b = blockIdx.x;
    if (tid < CH) {
        float s = 0.f;
        #pragma unroll
        for (int q = 0; q < 64; ++q) s += partial[(b * 64 + q) * CH + tid];
        pl[tid] = s * (1.f / (HWDIM * HWDIM));
    }
    __syncthreads();
    float h = fc2_b[tid];
    #pragma unroll
    for (int c = 0; c < CH; ++c) h += fc2_w[tid * CH + c] * pl[c];
    h2[tid] = fmaxf(h, 0.f);
    __syncthreads();
    if (tid < 13) {
        float o = fc3_b[tid];
        #pragma unroll
        for (int jj = 0; jj < HID; ++jj) o += fc3_w[tid * HID + jj] * h2[jj];
        out[b * 13 + tid] = o;
    }
}

// ---------------------------------------------------------------------------
extern "C" void kernel_launch(void* const* d_in, const int* in_sizes, int n_in,
                              void* d_out, int out_size, void* d_ws, size_t ws_size,
                              hipStream_t stream)
{
    const float* x     = (const float*)d_in[0];
    const float* masks = (const float*)d_in[1];
    const float* fc0_w = (const float*)d_in[2];
    const float* fc0_b = (const float*)d_in[3];
    const float* fc1_w = (const float*)d_in[4];
    const float* fc2_w = (const float*)d_in[5];
    const float* fc2_b = (const float*)d_in[6];
    const float* fc3_w = (const float*)d_in[7];
    const float* fc3_b = (const float*)d_in[8];

    float*    out     = (float*)d_out;
    float*    xf      = out + NB * 13;                             // output 1 region
    float*    buf0    = (float*)d_ws;                              // ping-pong state
    float*    partial = buf0 + (size_t)NB * HWDIM * HWDIM * CH;    // 2048*16 f
    _Float16* pw0     = (_Float16*)(partial + 2048 * CH);          // 16 KiB
    _Float16* pw1     = pw0 + 16 * 64 * 8;                         // 4 KiB

    nca_prepack<<<1, 256, 0, stream>>>(fc0_w, fc1_w, pw0, pw1);

    dim3 grid(HWDIM / 16, HWDIM / 16, NB), block(256);
    for (int s = 0; s < NSTEPS; ++s) {
        const float* in = (s == 0) ? x : ((s & 1) ? buf0 : xf);
        float* outp     = (s & 1) ? xf : buf0;
        const float* mk = masks + (size_t)s * NB * HWDIM * HWDIM;
        if (s == NSTEPS - 1)
            nca_step<true><<<grid, block, 0, stream>>>(in, outp, mk, pw0, fc0_b, pw1, partial);
        else
            nca_step<false><<<grid, block, 0, stream>>>(in, outp, mk, pw0, fc0_b, pw1, partial);
    }
    nca_head<<<NB, 128, 0, stream>>>(partial, fc2_w, fc2_b, fc3_w, fc3_b, out);
}